// Round 7
// baseline (2419.886 us; speedup 1.0000x reference)
//
#include <hip/hip_runtime.h>
#include <hip/hip_bf16.h>

typedef short  bf16x8 __attribute__((ext_vector_type(8)));
typedef float  f32x4  __attribute__((ext_vector_type(4)));
typedef int    i32x4  __attribute__((ext_vector_type(4)));

#define BB 64
#define SS 512
#define EE 300
#define HH 512

// workspace layout (bytes)
#define XT_OFF     ((size_t)0)
#define XT_BYTES   ((size_t)SS*10*4*1024)        // 20,971,520  x tiles [t][ks10][sg4][1KB]
#define SLOT_OFF   (XT_OFF + XT_BYTES)
#define SLOT_BYTES ((size_t)2*4*16*128*16)       // 262,144: [plane2][sg4][s16][uq128] 16B tagged slots
#define HT_OFF     (SLOT_OFF + SLOT_BYTES)
#define HT_BYTES   ((size_t)BB*HH*4)             // 131,072

__device__ __forceinline__ unsigned short f2bf(float x) {
  union { float f; unsigned u; } v; v.f = x;
  unsigned r = v.u + 0x7fffu + ((v.u >> 16) & 1u);   // RNE
  return (unsigned short)(r >> 16);
}
__device__ __forceinline__ float sigm(float x) { return 1.f / (1.f + __expf(-x)); }
__device__ __forceinline__ float tanh_fast(float x) { return 1.f - 2.f / (__expf(2.f * x) + 1.f); }

// ---- coherent (bypass L1/L2, served at coherence point) primitives ----
__device__ __forceinline__ void ld16_cc(i32x4* dst, const void* p) {
  asm volatile("global_load_dwordx4 %0, %1, off sc0 sc1"
               : "=v"(*dst) : "v"(p) : "memory");
}
__device__ __forceinline__ void st16_cc(void* p, i32x4 v) {
  asm volatile("global_store_dwordx4 %0, %1, off sc0 sc1"
               :: "v"(p), "v"(v) : "memory");
}

// ---- phase 0: embedding gather + cast, fragment-tiled output ----
// block layout: [t][ks(10)][sg(4)] of 1KB; within block [c(16)][kg(4)][j(8)] bf16
__global__ void gather_cast_kernel(const int* __restrict__ idx,
                                   const float* __restrict__ emb,
                                   unsigned short* __restrict__ xt) {
  __shared__ unsigned short lds_x[16 * 320];
  const int t     = blockIdx.x >> 2;
  const int mtile = blockIdx.x & 3;              // = sample-group
  const int tid   = threadIdx.x;                 // 0..255

  const int c2 = tid >> 4;
  const int e0 = tid & 15;
  const int b  = mtile * 16 + c2;
  const int vocab = idx[b * SS + t];
  const float* src = emb + (size_t)vocab * EE;
  for (int e = e0; e < 320; e += 16)
    lds_x[c2 * 320 + e] = (e < EE) ? f2bf(src[e]) : (unsigned short)0;
  __syncthreads();

  unsigned short* outb = xt + (((size_t)t * 10) * 4 + mtile) * 512;
  #pragma unroll
  for (int rr = 0; rr < 3; ++rr) {
    int O = rr * 4096 + tid * 16;                // byte offset within 10KB
    if (O < 10240) {
      int ks = O >> 10;
      int inblk = O & 1023;
      int c  = inblk >> 6;
      int kg = (inblk >> 4) & 3;
      bf16x8 v = *(const bf16x8*)&lds_x[c * 320 + ks * 32 + kg * 8];
      *(bf16x8*)((char*)outb + (size_t)ks * 4096 + inblk) = v;
    }
  }
}

// ---- phase 1: persistent recurrence, sample-group partitioned ----
// 64 wgs = 4 sample-groups (sg) x 16 unit-wgs (uw). wg owns (16 samples x 32 units).
// 8 waves: wave w owns units 32uw+4w..+3, full K=832, 16 gate-cols {4 gates x 4 units}.
// Cross-wg traffic only within a sample-group (16 consumers/slot). Tagged 16B
// slots {8B = 4 units bf16, 4B tag, 4B pad}; per-thread tag-spin on cooperative
// stage -> LDS (double-buffered, ONE barrier/step). Finalize fully in-register.
__launch_bounds__(512, 2)
__global__ void lstm_kernel(const unsigned short* __restrict__ xt,
                            char* __restrict__ slots,            // [2][4][16][128]*16B
                            float* __restrict__ hT,              // [BB][HH] fp32
                            const float* __restrict__ Wih,
                            const float* __restrict__ Whh,
                            const float* __restrict__ bih,
                            const float* __restrict__ bhh) {
  __shared__ __attribute__((aligned(16))) char hstage[2][16 * 1280];  // [kt16][s16(80B)]

  const int p   = blockIdx.x;              // 0..63
  const int sg  = p & 3;                   // sample-group: samples 16sg..+15
  const int uw  = p >> 2;                  // unit-wg: units 32uw..+31
  const int tid = threadIdx.x;             // 0..511
  const int l   = tid & 63;
  const int w   = tid >> 6;                // 0..7
  const int c   = l & 15;                  // B col: gate=c>>2, local unit=c&3
  const int kg  = l >> 4;                  // k-group
  const int U0  = 32 * uw + 4 * w;         // wave's first global unit

  // ---- preload W fragments (constant all 512 steps) ----
  const int Grow = ((c >> 2) << 9) + U0 + (c & 3);
  const float* wih_row = Wih + (size_t)Grow * EE;
  const float* whh_row = Whh + (size_t)Grow * HH;

  bf16x8 Bx[10], Bh[16];
  #pragma unroll
  for (int ks = 0; ks < 10; ++ks) {
    int k0 = 32 * ks + 8 * kg;
    bf16x8 vb;
    #pragma unroll
    for (int j = 0; j < 8; ++j) {
      int k = k0 + j;
      vb[j] = (short)((k < EE) ? f2bf(wih_row[k]) : (unsigned short)0);
    }
    Bx[ks] = vb;
  }
  #pragma unroll
  for (int kt = 0; kt < 16; ++kt) {
    int k0 = 32 * kt + 8 * kg;
    bf16x8 vb;
    #pragma unroll
    for (int j = 0; j < 8; ++j) vb[j] = (short)f2bf(whh_row[k0 + j]);
    Bh[kt] = vb;
  }
  const float bsum = bih[Grow] + bhh[Grow];

  // x fragment base (ushort units): block ((it*10+ks)*4 + sg), inblock (c,kg)
  const unsigned short* xbase = xt + sg * 512 + c * 32 + kg * 8;

  // staging: thread handles slots i = tid + 512j (j=0..3) of its sg region
  const int uq_t = tid & 127;
  const int s0_t = tid >> 7;               // 0..3 (slot j adds 4j)
  const int lwb  = (uq_t >> 3) * 1280 + ((uq_t >> 1) & 3) * 16 + (uq_t & 1) * 8
                 + s0_t * 80;
  const size_t sg_off = (size_t)sg * 32768;
  const char* rbase = slots + sg_off + (size_t)tid * 16;
  // A-fragment LDS read offset: sample row = c, k-group = kg
  const int lr = c * 80 + kg * 16;
  // slot store base: uq = 8uw + w
  char* const wbase = slots + sg_off + (size_t)(8 * uw + w) * 16;

  f32x4 cst = {0.f, 0.f, 0.f, 0.f};        // cell state rows 0..3 (valid c<4)

  for (int it = 0; it < SS; ++it) {
    // --- issue this step's slot loads early (hide under x-MFMA) ---
    const char* rp = rbase + (size_t)(it & 1) * 131072;
    i32x4 d0, d1, d2, d3;
    ld16_cc(&d0, rp);
    ld16_cc(&d1, rp + 8192);
    ld16_cc(&d2, rp + 16384);
    ld16_cc(&d3, rp + 24576);

    // --- x part (plain cached loads, coalesced 1KB per instr) ---
    f32x4 ax0 = {0.f, 0.f, 0.f, 0.f};
    f32x4 ax1 = {0.f, 0.f, 0.f, 0.f};
    const unsigned short* xq = xbase + (size_t)it * 20480;
    #pragma unroll
    for (int ks = 0; ks < 10; ks += 2) {
      bf16x8 a0 = *(const bf16x8*)(xq + ks * 2048);
      bf16x8 a1 = *(const bf16x8*)(xq + (ks + 1) * 2048);
      ax0 = __builtin_amdgcn_mfma_f32_16x16x32_bf16(a0, Bx[ks],     ax0, 0, 0, 0);
      ax1 = __builtin_amdgcn_mfma_f32_16x16x32_bf16(a1, Bx[ks + 1], ax1, 0, 0, 0);
    }
    __builtin_amdgcn_sched_barrier(0);

    // --- per-thread tag-spin on own 4 slots (laggards only re-issue) ---
    asm volatile("s_waitcnt vmcnt(0)" ::: "memory");
    while (!((d0[2] == it) & (d1[2] == it) & (d2[2] == it) & (d3[2] == it))) {
      __builtin_amdgcn_s_sleep(1);
      ld16_cc(&d0, rp);
      ld16_cc(&d1, rp + 8192);
      ld16_cc(&d2, rp + 16384);
      ld16_cc(&d3, rp + 24576);
      asm volatile("s_waitcnt vmcnt(0)" ::: "memory");
    }

    // --- stage 8B payloads into fragment-layout LDS (double-buffered) ---
    char* hs = hstage[it & 1];
    { int* q = (int*)(hs + lwb);        q[0] = d0[0]; q[1] = d0[1]; }
    { int* q = (int*)(hs + lwb + 320);  q[0] = d1[0]; q[1] = d1[1]; }
    { int* q = (int*)(hs + lwb + 640);  q[0] = d2[0]; q[1] = d2[1]; }
    { int* q = (int*)(hs + lwb + 960);  q[0] = d3[0]; q[1] = d3[1]; }
    __syncthreads();

    // --- h part: 16 ds_read_b128 fragments -> MFMA ---
    f32x4 ah0 = {0.f, 0.f, 0.f, 0.f};
    f32x4 ah1 = {0.f, 0.f, 0.f, 0.f};
    #pragma unroll
    for (int kt = 0; kt < 16; kt += 2) {
      bf16x8 a0 = *(const bf16x8*)(hs + kt * 1280 + lr);
      bf16x8 a1 = *(const bf16x8*)(hs + (kt + 1) * 1280 + lr);
      ah0 = __builtin_amdgcn_mfma_f32_16x16x32_bf16(a0, Bh[kt],     ah0, 0, 0, 0);
      ah1 = __builtin_amdgcn_mfma_f32_16x16x32_bf16(a1, Bh[kt + 1], ah1, 0, 0, 0);
    }
    f32x4 acc = (ax0 + ax1) + (ah0 + ah1);

    // --- finalize in-register: lane c holds gate c>>2 of unit U0+(c&3) ---
    char* wp = wbase + (size_t)((it + 1) & 1) * 131072;
    #pragma unroll
    for (int r = 0; r < 4; ++r) {
      float v  = acc[r] + bsum;
      float vf = __shfl_xor(v, 4, 64);
      float vg = __shfl_xor(v, 8, 64);
      float vo = __shfl_xor(v, 12, 64);
      float ig = sigm(v);
      float fg = sigm(vf);
      float gt = tanh_fast(vg);
      float og = sigm(vo);
      cst[r] = fg * cst[r] + ig * gt;
      float h = og * tanh_fast(cst[r]);

      if (it != SS - 1) {
        int hv  = (int)f2bf(h);
        int o1  = __shfl_xor(hv, 1, 64);
        int pk  = (hv & 0xffff) | (o1 << 16);       // units {0,1} of quad on c==0
        int pk2 = __shfl_xor(pk, 2, 64);            // units {2,3} of quad
        if (c == 0) {
          i32x4 val; val[0] = pk; val[1] = pk2; val[2] = it + 1; val[3] = 0;
          st16_cc(wp + (4 * kg + r) * 2048, val);   // slot (s=4kg+r, uq=8uw+w)
        }
      } else if (c < 4) {
        hT[(size_t)(16 * sg + 4 * kg + r) * HH + U0 + c] = h;
      }
    }
  }
}

// ---- phase 2: y[b] = hT[b,:] . Wout + bout ----
__global__ void outproj_kernel(const float* __restrict__ hT,
                               const float* __restrict__ Wout,
                               const float* __restrict__ bout,
                               float* __restrict__ y) {
  int b = blockIdx.x;
  int t = threadIdx.x;   // 64
  float s = 0.f;
  for (int j = t; j < HH; j += 64) s += hT[b * HH + j] * Wout[j];
  #pragma unroll
  for (int off = 32; off > 0; off >>= 1) s += __shfl_down(s, off, 64);
  if (t == 0) y[b] = s + bout[0];
}

extern "C" void kernel_launch(void* const* d_in, const int* in_sizes, int n_in,
                              void* d_out, int out_size, void* d_ws, size_t ws_size,
                              hipStream_t stream) {
  const int*   idx  = (const int*)d_in[0];
  const float* emb  = (const float*)d_in[1];
  const float* Wih  = (const float*)d_in[2];
  const float* Whh  = (const float*)d_in[3];
  const float* bih  = (const float*)d_in[4];
  const float* bhh  = (const float*)d_in[5];
  const float* Wout = (const float*)d_in[6];
  const float* bout = (const float*)d_in[7];
  float* y = (float*)d_out;

  char* ws = (char*)d_ws;
  unsigned short* xt = (unsigned short*)(ws + XT_OFF);
  char* slots        = ws + SLOT_OFF;
  float* hT          = (float*)(ws + HT_OFF);

  // deterministic per-call init: both planes zeroed (h(0)=0, tags=0; kills
  // stale tags from previous graph replay)
  hipMemsetAsync(slots, 0, SLOT_BYTES, stream);

  gather_cast_kernel<<<SS * 4, 256, 0, stream>>>(idx, emb, xt);
  lstm_kernel<<<64, 512, 0, stream>>>(xt, slots, hT, Wih, Whh, bih, bhh);
  outproj_kernel<<<BB, 64, 0, stream>>>(hT, Wout, bout, y);
}